// Round 13
// baseline (151.802 us; speedup 1.0000x reference)
//
#include <hip/hip_runtime.h>

#define BATCH 8
#define NPTS 4096
#define KSEL 5          // K_NN; self-candidate excluded in-scan
#define ALPHA 1.05f
#define NSEG 16         // waves per block
#define TPB (NSEG * 64)        // 1024 threads
#define PPB 64          // sorted points per block (1 per lane), fast path
#define AWIN 256        // phase-a bound-estimation window (candidates)
#define SEGLEN (NPTS / NSEG)   // 256 (fallback kernel)
#define FPPB 128        // fallback points per block (2 per lane)
#define STATS_T 1024

// ---------------------------------------------------------------------------
// f32 3-input min/med/max (single VOP3 instr each). Selection runs in FLOAT
// domain (g-scores can be negative). No NaNs present.
// ---------------------------------------------------------------------------
static __device__ __forceinline__ float min3f(float a, float b, float c) {
  float d;
  asm("v_min3_f32 %0, %1, %2, %3" : "=v"(d) : "v"(a), "v"(b), "v"(c));
  return d;
}
static __device__ __forceinline__ float med3f(float a, float b, float c) {
  float d;
  asm("v_med3_f32 %0, %1, %2, %3" : "=v"(d) : "v"(a), "v"(b), "v"(c));
  return d;
}
static __device__ __forceinline__ float max3f(float a, float b, float c) {
  float d;
  asm("v_max3_f32 %0, %1, %2, %3" : "=v"(d) : "v"(a), "v"(b), "v"(c));
  return d;
}

typedef float f16v __attribute__((ext_vector_type(16)));  // one 64B packed group

// Fused branchless insert of two candidates into sorted m[0..KSEL-1].
static __device__ __forceinline__ void insert2f(float m[KSEL], float tA, float tB) {
#pragma unroll
  for (int k = 0; k < KSEL - 1; ++k) {
    const float mk = m[k];
    m[k] = min3f(mk, tA, tB);
    const float nA = med3f(mk, tA, tB);
    const float nB = max3f(mk, tA, tB);
    tA = nA;
    tB = nB;
  }
  m[KSEL - 1] = min3f(m[KSEL - 1], tA, tB);
}

// One group (4 candidates) against ONE point (g = r_j - 2*dot, 3 fma/cand).
template <bool EXCL>
static __device__ __forceinline__ void group4_1p(const f16v c, const int jb, const int i,
                                                 const float x2, const float y2, const float z2,
                                                 float m[KSEL]) {
  float g[4];
#pragma unroll
  for (int t = 0; t < 4; ++t) {
    g[t] = fmaf(c[t], x2, fmaf(c[4 + t], y2, fmaf(c[8 + t], z2, c[12 + t])));
  }
  if (EXCL) {
#pragma unroll
    for (int t = 0; t < 4; ++t)
      if (jb + t == i) g[t] = __builtin_inff();
  }
  insert2f(m, g[0], g[1]);
  insert2f(m, g[2], g[3]);
}

// ---------------------------------------------------------------------------
// R12 post-mortem: ledger = 51us fixed + 41us knn + 2.5us stats. Brute-force
// issue floor ~33us -> micro-polish is worth <=5us. R13 goes algorithmic:
// EXACT pruning. Sort points by x; a candidate j can enter point i's top-5
// only if (x_j-x_i)^2 <= d5_ub(i). Phase a scans a fixed 256-cand window to
// get d5_ub (min over 16 per-wave 5th-smallest values — any-subset 5th >=
// union 5th >= final d5, so it IS an upper bound). Inflated reach s_i =
// sqrt(d5_ub)*1.001+1e-4 makes every excluded candidate STRICTLY worse than
// the cutoff (covers all fp slop) -> exact same top-5 multiset. Scatter back
// through the sort permutation -> value[] and all downstream accumulation
// orders bit-identical to R12.
// ---------------------------------------------------------------------------

// Kernel 0: per-batch bitonic sort by x. 1 block/batch, 1024 threads.
// key = monotone-flipped float(x) in high 32 bits, original index low 32.
__global__ __launch_bounds__(1024) void sort_kernel(const float* __restrict__ pc,
                                                    float* __restrict__ spk,
                                                    unsigned* __restrict__ sorg,
                                                    float* __restrict__ out) {
  __shared__ unsigned long long kv[NPTS];   // 32 KB
  const int b   = blockIdx.x;
  const int tid = threadIdx.x;
  if (b == 0 && tid == 0) out[0] = 0.0f;
  const float* __restrict__ base = pc + (size_t)b * (NPTS * 3);

#pragma unroll
  for (int e = 0; e < NPTS / 1024; ++e) {
    const int idx = tid + e * 1024;
    unsigned u = __float_as_uint(base[idx * 3 + 0]);
    u ^= (u >> 31) ? 0xFFFFFFFFu : 0x80000000u;   // monotone float->uint
    kv[idx] = ((unsigned long long)u << 32) | (unsigned)idx;
  }
  __syncthreads();

  for (int k = 2; k <= NPTS; k <<= 1) {
    for (int j = k >> 1; j > 0; j >>= 1) {
#pragma unroll
      for (int e = 0; e < NPTS / 1024; ++e) {
        const int idx = tid + e * 1024;
        const int l = idx ^ j;
        if (l > idx) {
          const bool asc = ((idx & k) == 0);
          const unsigned long long a = kv[idx];
          const unsigned long long c = kv[l];
          if ((a > c) == asc) { kv[idx] = c; kv[l] = a; }
        }
      }
      __syncthreads();
    }
  }

  // Emit sorted packed groups {x[4],y[4],z[4],r[4]} + permutation.
#pragma unroll
  for (int e = 0; e < NPTS / 1024; ++e) {
    const int s = tid + e * 1024;
    const unsigned orig = (unsigned)kv[s];
    const float x = base[orig * 3 + 0];
    const float y = base[orig * 3 + 1];
    const float z = base[orig * 3 + 2];
    float* dst = spk + (size_t)b * (NPTS * 4) + (size_t)(s >> 2) * 16;
    const int t = s & 3;
    dst[t + 0]  = x;
    dst[t + 4]  = y;
    dst[t + 8]  = z;
    dst[t + 12] = fmaf(z, z, fmaf(y, y, x * x));  // same form as r_i below
    sorg[b * NPTS + s] = orig;
  }
}

// Kernel 1: pruned exact 5-NN. grid = 512 (8 batches x 64 tiles of 64 sorted
// points, 1/lane); 1024 thr; 2 blocks/CU (8 waves/SIMD, R11 regime).
__global__ __launch_bounds__(TPB, 8) void knn_pruned(const float* __restrict__ spk,
                                                     const unsigned* __restrict__ sorg,
                                                     float* __restrict__ value) {
  __shared__ union __align__(64) {
    float pk[NPTS * 4];             // 64 KB sorted packed groups
    float cand[NSEG][PPB][KSEL];    // 20 KB (used only after phase-b scan)
  } sh;
  __shared__ float g5buf[NSEG][PPB];  // 4 KB per-wave phase-a bounds
  __shared__ float sblo, sbhi;

  const int tid = threadIdx.x;
  const int pt  = tid & 63;
  const int seg = __builtin_amdgcn_readfirstlane(tid >> 6);  // wave-uniform
  const int b    = blockIdx.x >> 6;   // 64 tiles per batch
  const int tile = blockIdx.x & 63;
  const int i    = tile * PPB + pt;   // own SORTED rank (all waves share 64 pts)

  const float* __restrict__ pb = spk + (size_t)b * (NPTS * 4);

  // Stage the whole batch's packed array (coalesced float4).
  {
    const float4* __restrict__ src = (const float4*)pb;
    float4* dst = (float4*)sh.pk;
#pragma unroll
    for (int e = 0; e < (NPTS * 4) / (TPB * 4); ++e)
      dst[tid + e * TPB] = src[tid + e * TPB];
  }
  __syncthreads();

  // Own point coords (per-lane gather from packed LDS).
  const int gi = (i >> 2) * 16 + (i & 3);
  const float xi = sh.pk[gi + 0];
  const float yi = sh.pk[gi + 4];
  const float zi = sh.pk[gi + 8];
  const float x2 = -2.0f * xi, y2 = -2.0f * yi, z2 = -2.0f * zi;  // exact
  const float ri = fmaf(zi, zi, fmaf(yi, yi, xi * xi));

  const f16v* __restrict__ sg = (const f16v*)sh.pk;
  const int T = tile * PPB;

  // ---- Phase a: fixed 256-candidate window around the tile -> d5_ub ----
  float m[KSEL];
#pragma unroll
  for (int k = 0; k < KSEL; ++k) m[k] = __builtin_inff();

  int a0 = T - 96;
  if (a0 < 0) a0 = 0;
  if (a0 > NPTS - AWIN) a0 = NPTS - AWIN;   // window always contains own 64 ranks
  const int a0g = a0 >> 2;
#pragma unroll
  for (int q = 0; q < (AWIN / 4) / NSEG; ++q) {   // 4 groups per wave
    const int gg = a0g + seg * ((AWIN / 4) / NSEG) + q;
    const int jb = gg * 4;
    const f16v c = sg[gg];
    if ((unsigned)(jb - T) < (unsigned)PPB)   // group overlaps own ranks (4-aligned)
      group4_1p<true>(c, jb, i, x2, y2, z2, m);
    else
      group4_1p<false>(c, jb, i, x2, y2, z2, m);
  }
  g5buf[seg][pt] = m[KSEL - 1];   // this wave's 5th smallest (finite: >=15 real cands)
  __syncthreads();

  // d5_ub = min over waves (5th-of-subset >= 5th-of-union >= final d5).
  float g5 = g5buf[0][pt];
#pragma unroll
  for (int s = 1; s < NSEG; ++s) g5 = fminf(g5, g5buf[s][pt]);
  const float d5 = g5 + ri;
  // Inflate reach past all fp slop: excluded => strictly worse than cutoff.
  const float si = sqrtf(fmaxf(d5, 0.0f)) * 1.001f + 1e-4f;
  const float lo = xi - si;
  const float hi = xi + si;

  // Block window = [min lo, max hi] over the 64 points (wave 0 reduces).
  if (tid < 64) {
    float vlo = lo, vhi = hi;
#pragma unroll
    for (int o = 32; o > 0; o >>= 1) {
      vlo = fminf(vlo, __shfl_xor(vlo, o));
      vhi = fmaxf(vhi, __shfl_xor(vhi, o));
    }
    if (tid == 0) { sblo = vlo; sbhi = vhi; }
  }
  __syncthreads();
  const float blo = sblo, bhi = sbhi;

  // Binary search sorted x (all threads redundantly; identical results).
  int l1 = 0, h1 = NPTS;                 // lower_bound(blo)
  while (l1 < h1) {
    const int mid = (l1 + h1) >> 1;
    const float xv = sh.pk[(mid >> 2) * 16 + (mid & 3)];
    if (xv < blo) l1 = mid + 1; else h1 = mid;
  }
  int l2 = 0, h2 = NPTS;                 // upper_bound(bhi)
  while (l2 < h2) {
    const int mid = (l2 + h2) >> 1;
    const float xv = sh.pk[(mid >> 2) * 16 + (mid & 3)];
    if (xv <= bhi) l2 = mid + 1; else h2 = mid;
  }
  const int glo = l1 >> 2;               // group range (round out: superset ok)
  const int ghi = (l2 + 3) >> 2;

  // ---- Phase b: scan the exact window, fresh lists, round-robin waves ----
#pragma unroll
  for (int k = 0; k < KSEL; ++k) m[k] = __builtin_inff();
  for (int gg = glo + seg; gg < ghi; gg += NSEG) {
    const f16v c = sg[gg];
    const int jb = gg * 4;
    if ((unsigned)(jb - T) < (unsigned)PPB)
      group4_1p<true>(c, jb, i, x2, y2, z2, m);
    else
      group4_1p<false>(c, jb, i, x2, y2, z2, m);
  }
  __syncthreads();   // all waves done reading pk

#pragma unroll
  for (int k = 0; k < KSEL; ++k) sh.cand[seg][pt][k] = m[k];
  __syncthreads();

  // 16-way tree merge over 64 point-columns.
  for (int st = 1; st < NSEG; st <<= 1) {
    const int pairs = NSEG / (2 * st);
    if (tid < pairs * PPB) {
      const int q = tid >> 6;
      const int p = tid & 63;
      float* A = &sh.cand[2 * st * q][p][0];
      const float* B = &sh.cand[2 * st * q + st][p][0];
      float mm[KSEL];
#pragma unroll
      for (int k = 0; k < KSEL; ++k) mm[k] = A[k];
#pragma unroll
      for (int k = 0; k < KSEL; ++k) {
        float t = B[k];
#pragma unroll
        for (int u = 0; u < KSEL - 1; ++u) {
          const float lo2 = fminf(mm[u], t);
          t = fmaxf(mm[u], t);
          mm[u] = lo2;
        }
        mm[KSEL - 1] = fminf(mm[KSEL - 1], t);
      }
#pragma unroll
      for (int k = 0; k < KSEL; ++k) A[k] = mm[k];
    }
    __syncthreads();
  }

  // mean(d) = mean(g) + r_i (ascending sum); scatter to ORIGINAL index so
  // downstream accumulation order is bit-identical to the unsorted kernels.
  if (tid < PPB) {
    float s5 = 0.f;
#pragma unroll
    for (int k = 0; k < KSEL; ++k) s5 += sh.cand[0][tid][k];
    value[b * NPTS + sorg[b * NPTS + i]] = s5 * 0.2f + ri;
  }
}

// Kernel 2: per-batch stats on value[] (original order). 1024 threads.
__global__ __launch_bounds__(STATS_T) void stats_v(const float* __restrict__ value,
                                                   const float* __restrict__ weights,
                                                   float* __restrict__ out) {
  __shared__ float vbuf[NPTS];   // 16 KB cached values
  __shared__ float red[STATS_T];
  const int b   = blockIdx.x;
  const int tid = threadIdx.x;

  float s = 0.f;
  for (int j = tid; j < NPTS; j += STATS_T) {
    const float v = value[b * NPTS + j];
    vbuf[j] = v;
    s += v;
  }
  red[tid] = s;
  __syncthreads();
  for (int off = STATS_T / 2; off > 0; off >>= 1) {
    if (tid < off) red[tid] += red[tid + off];
    __syncthreads();
  }
  const float mean = red[0] * (1.0f / NPTS);
  __syncthreads();

  float s2 = 0.f;
  for (int j = tid; j < NPTS; j += STATS_T) {
    const float d = vbuf[j] - mean;
    s2 += d * d;
  }
  red[tid] = s2;
  __syncthreads();
  for (int off = STATS_T / 2; off > 0; off >>= 1) {
    if (tid < off) red[tid] += red[tid + off];
    __syncthreads();
  }
  const float thr = mean + ALPHA * sqrtf(red[0] * (1.0f / (NPTS - 1)));
  __syncthreads();

  float s3 = 0.f;
  for (int j = tid; j < NPTS; j += STATS_T) {
    const float vv = vbuf[j];
    if (vv > thr) s3 += vv;
  }
  red[tid] = s3;
  __syncthreads();
  for (int off = STATS_T / 2; off > 0; off >>= 1) {
    if (tid < off) red[tid] += red[tid + off];
    __syncthreads();
  }
  if (tid == 0) {
    atomicAdd(out, red[0] * (1.0f / NPTS) * weights[b] * (1.0f / BATCH));
  }
}

// ---------------------------------------------------------------------------
// Fallback (ws too small): R10 brute-force kernels, unchanged.
// ---------------------------------------------------------------------------
template <bool EXCL>
static __device__ __forceinline__ void knn_group4_sc(const f16v c, const int jb,
                                                     const int i0, const int i1,
                                                     const float x20, const float y20, const float z20,
                                                     const float x21, const float y21, const float z21,
                                                     float m0[KSEL], float m1[KSEL]) {
  float g0[4], g1[4];
#pragma unroll
  for (int t = 0; t < 4; ++t) {
    const float xj = c[t], yj = c[4 + t], zj = c[8 + t], rj = c[12 + t];
    g0[t] = fmaf(xj, x20, fmaf(yj, y20, fmaf(zj, z20, rj)));
    g1[t] = fmaf(xj, x21, fmaf(yj, y21, fmaf(zj, z21, rj)));
  }
  if (EXCL) {
#pragma unroll
    for (int t = 0; t < 4; ++t) {
      if (jb + t == i0) g0[t] = __builtin_inff();
      if (jb + t == i1) g1[t] = __builtin_inff();
    }
  }
  insert2f(m0, g0[0], g0[1]);
  insert2f(m0, g0[2], g0[3]);
  insert2f(m1, g1[0], g1[1]);
  insert2f(m1, g1[2], g1[3]);
}

template <bool EXCL>
static __device__ __forceinline__ void scan_seg_sc2(const f16v* __restrict__ sg,
                                                    const int g0i, const int j0,
                                                    const int i0, const int i1,
                                                    const float x20, const float y20, const float z20,
                                                    const float x21, const float y21, const float z21,
                                                    float m0[KSEL], float m1[KSEL]) {
#pragma unroll 4
  for (int g = 0; g < SEGLEN / 4; ++g) {
    const f16v c = sg[g0i + g];
    knn_group4_sc<EXCL>(c, j0 + 4 * g, i0, i1, x20, y20, z20, x21, y21, z21, m0, m1);
  }
}

__global__ __launch_bounds__(TPB) void knn_value_sc2(const float* __restrict__ pc,
                                                     float* __restrict__ value,
                                                     float* __restrict__ out) {
  __shared__ union __align__(64) {
    float pk[NPTS * 4];
    float cand[NSEG][FPPB][KSEL];
  } sh;

  const int tid = threadIdx.x;
  const int pt  = tid & 63;
  const int seg = __builtin_amdgcn_readfirstlane(tid >> 6);
  const int b    = blockIdx.x >> 5;
  const int tile = blockIdx.x & 31;
  const int i0   = tile * FPPB + pt;
  const int i1   = i0 + 64;

  if (blockIdx.x == 0 && tid == 0) out[0] = 0.0f;

  const float* __restrict__ base = pc + (size_t)b * (NPTS * 3);
#pragma unroll
  for (int k = 0; k < NPTS / TPB; ++k) {
    const int p = tid + k * TPB;
    const float x = base[p * 3 + 0];
    const float y = base[p * 3 + 1];
    const float z = base[p * 3 + 2];
    float* dst = &sh.pk[(p >> 2) * 16];
    const int s = p & 3;
    dst[s + 0]  = x;
    dst[s + 4]  = y;
    dst[s + 8]  = z;
    dst[s + 12] = fmaf(z, z, fmaf(y, y, x * x));
  }
  __syncthreads();

  const int gi0 = (i0 >> 2) * 16 + (i0 & 3);
  const int gi1 = (i1 >> 2) * 16 + (i1 & 3);
  const float xi0 = sh.pk[gi0 + 0], yi0 = sh.pk[gi0 + 4], zi0 = sh.pk[gi0 + 8];
  const float xi1 = sh.pk[gi1 + 0], yi1 = sh.pk[gi1 + 4], zi1 = sh.pk[gi1 + 8];
  const float x20 = -2.0f * xi0, y20 = -2.0f * yi0, z20 = -2.0f * zi0;
  const float x21 = -2.0f * xi1, y21 = -2.0f * yi1, z21 = -2.0f * zi1;

  float m0[KSEL], m1[KSEL];
#pragma unroll
  for (int k = 0; k < KSEL; ++k) { m0[k] = __builtin_inff(); m1[k] = __builtin_inff(); }

  const int j0  = seg * SEGLEN;
  const int g0i = seg * (SEGLEN / 4);
  const f16v* __restrict__ sg = (const f16v*)sh.pk;

  if (seg == (tile >> 1)) {
    scan_seg_sc2<true>(sg, g0i, j0, i0, i1, x20, y20, z20, x21, y21, z21, m0, m1);
  } else {
    scan_seg_sc2<false>(sg, g0i, j0, i0, i1, x20, y20, z20, x21, y21, z21, m0, m1);
  }
  __syncthreads();

#pragma unroll
  for (int k = 0; k < KSEL; ++k) {
    sh.cand[seg][pt][k]      = m0[k];
    sh.cand[seg][pt + 64][k] = m1[k];
  }
  __syncthreads();

  for (int st = 1; st < NSEG; st <<= 1) {
    const int pairs = NSEG / (2 * st);
    if (tid < pairs * FPPB) {
      const int q = tid >> 7;
      const int p = tid & (FPPB - 1);
      float* A = &sh.cand[2 * st * q][p][0];
      const float* B = &sh.cand[2 * st * q + st][p][0];
      float mm[KSEL];
#pragma unroll
      for (int k = 0; k < KSEL; ++k) mm[k] = A[k];
#pragma unroll
      for (int k = 0; k < KSEL; ++k) {
        float t = B[k];
#pragma unroll
        for (int u = 0; u < KSEL - 1; ++u) {
          const float lo = fminf(mm[u], t);
          t = fmaxf(mm[u], t);
          mm[u] = lo;
        }
        mm[KSEL - 1] = fminf(mm[KSEL - 1], t);
      }
#pragma unroll
      for (int k = 0; k < KSEL; ++k) A[k] = mm[k];
    }
    __syncthreads();
  }

  if (tid < FPPB) {
    float s5 = 0.f;
#pragma unroll
    for (int k = 0; k < KSEL; ++k) s5 += sh.cand[0][tid][k];
    float xx, yy, zz;
    if (tid < 64) { xx = xi0; yy = yi0; zz = zi0; }
    else          { xx = xi1; yy = yi1; zz = zi1; }
    const float ri = fmaf(zz, zz, fmaf(yy, yy, xx * xx));
    value[b * NPTS + tile * FPPB + tid] = s5 * 0.2f + ri;
  }
}

extern "C" void kernel_launch(void* const* d_in, const int* in_sizes, int n_in,
                              void* d_out, int out_size, void* d_ws, size_t ws_size,
                              hipStream_t stream) {
  const float* pc      = (const float*)d_in[0];   // [8,4096,3] f32
  const float* weights = (const float*)d_in[1];   // [8] f32
  float* out   = (float*)d_out;                   // scalar f32
  float* wsf   = (float*)d_ws;

  const size_t NB = (size_t)BATCH * NPTS;          // 32768
  // layout: value [NB floats] | spk [NB*4 floats] | sorg [NB uints]
  const size_t need = NB * 4 + NB * 16 + NB * 4;   // 768 KB

  if (ws_size >= need) {
    float*    value = wsf;
    float*    spk   = wsf + NB;
    unsigned* sorg  = (unsigned*)(wsf + NB * 5);
    sort_kernel<<<dim3(BATCH), dim3(1024), 0, stream>>>(pc, spk, sorg, out);
    knn_pruned<<<dim3(BATCH * 64), dim3(TPB), 0, stream>>>(spk, sorg, value);
    stats_v<<<dim3(BATCH), dim3(STATS_T), 0, stream>>>(value, weights, out);
  } else {
    float* value = wsf;                           // 128 KB (R10 layout)
    knn_value_sc2<<<dim3(BATCH * (NPTS / FPPB)), dim3(TPB), 0, stream>>>(pc, value, out);
    stats_v<<<dim3(BATCH), dim3(STATS_T), 0, stream>>>(value, weights, out);
  }
}

// Round 14
// 112.447 us; speedup vs baseline: 1.3500x; 1.3500x over previous
//
#include <hip/hip_runtime.h>

#define BATCH 8
#define NPTS 4096
#define KSEL 5          // K_NN; self-candidate excluded in-scan
#define ALPHA 1.05f
#define NSEG 16         // waves per block
#define TPB (NSEG * 64)        // 1024 threads
#define PPB 128         // points per block (2 per lane), fast path
#define NBINS 256       // x-buckets per batch
#define AWIN 256        // phase-a bound window (scattered ranks)
#define SEGLEN (NPTS / NSEG)   // 256 (fallback kernel)
#define STATS_T 1024

// ---------------------------------------------------------------------------
// f32 3-input min/med/max (single VOP3 instr each).
// ---------------------------------------------------------------------------
static __device__ __forceinline__ float min3f(float a, float b, float c) {
  float d;
  asm("v_min3_f32 %0, %1, %2, %3" : "=v"(d) : "v"(a), "v"(b), "v"(c));
  return d;
}
static __device__ __forceinline__ float med3f(float a, float b, float c) {
  float d;
  asm("v_med3_f32 %0, %1, %2, %3" : "=v"(d) : "v"(a), "v"(b), "v"(c));
  return d;
}
static __device__ __forceinline__ float max3f(float a, float b, float c) {
  float d;
  asm("v_max3_f32 %0, %1, %2, %3" : "=v"(d) : "v"(a), "v"(b), "v"(c));
  return d;
}

typedef float f16v __attribute__((ext_vector_type(16)));  // one 64B packed group

// Fused branchless insert of two candidates into sorted m[0..KSEL-1].
static __device__ __forceinline__ void insert2f(float m[KSEL], float tA, float tB) {
#pragma unroll
  for (int k = 0; k < KSEL - 1; ++k) {
    const float mk = m[k];
    m[k] = min3f(mk, tA, tB);
    const float nA = med3f(mk, tA, tB);
    const float nB = max3f(mk, tA, tB);
    tA = nA;
    tB = nB;
  }
  m[KSEL - 1] = min3f(m[KSEL - 1], tA, tB);
}

// One packed group (4 candidates) against TWO points. g = r_j - 2*dot.
template <bool EXCL>
static __device__ __forceinline__ void knn_group4_sc(const f16v c, const int jb,
                                                     const int i0, const int i1,
                                                     const float x20, const float y20, const float z20,
                                                     const float x21, const float y21, const float z21,
                                                     float m0[KSEL], float m1[KSEL]) {
  float g0[4], g1[4];
#pragma unroll
  for (int t = 0; t < 4; ++t) {
    const float xj = c[t], yj = c[4 + t], zj = c[8 + t], rj = c[12 + t];
    g0[t] = fmaf(xj, x20, fmaf(yj, y20, fmaf(zj, z20, rj)));
    g1[t] = fmaf(xj, x21, fmaf(yj, y21, fmaf(zj, z21, rj)));
  }
  if (EXCL) {
#pragma unroll
    for (int t = 0; t < 4; ++t) {
      if (jb + t == i0) g0[t] = __builtin_inff();
      if (jb + t == i1) g1[t] = __builtin_inff();
    }
  }
  insert2f(m0, g0[0], g0[1]);
  insert2f(m0, g0[2], g0[3]);
  insert2f(m1, g1[0], g1[1]);
  insert2f(m1, g1[2], g1[3]);
}

// ---------------------------------------------------------------------------
// R13 post-mortem: (1) bitonic sort = 53.7us at 0.45% VALU (78 barrier stages
// on 8 blocks). (2) knn_pruned pruned NOTHING: per-wave 5th-of-16-candidates
// bound ~1.4 (full y,z spread) vs true d5 ~0.03 -> windows ~full batch.
// R14: (1) counting-sort bucket scatter, 5 barriers. (2) phase-a bound =
// EXACT top-5 of the 256-rank window via the proven 16-way tree merge ->
// d5_ub ~= true d5 -> windows ~400-800/4096. Bin-granular windows are exact
// supersets (monotone fp mul + clamp). Atomic scatter order nondeterministic
// but final top-5 multiset / ascending sum / original-index scatter are
// invariant -> bit-identical output.
// ---------------------------------------------------------------------------

// Kernel 0: bucket scatter. 1 block/batch, 1024 threads, 5 barriers.
__global__ __launch_bounds__(1024) void bucket_kernel(const float* __restrict__ pc,
                                                      float* __restrict__ spk,
                                                      unsigned* __restrict__ sorg,
                                                      unsigned* __restrict__ binoff,
                                                      float* __restrict__ meta,
                                                      float* __restrict__ out) {
  __shared__ float wmn[NSEG], wmx[NSEG];
  __shared__ unsigned bins[NBINS];     // counts, then cursors
  __shared__ unsigned boff[NBINS + 1];
  __shared__ float sxmin, sxscl;

  const int tid  = threadIdx.x;
  const int b    = blockIdx.x;
  const int lane = tid & 63;
  const int wid  = tid >> 6;
  if (b == 0 && tid == 0) out[0] = 0.0f;
  const float* __restrict__ base = pc + (size_t)b * (NPTS * 3);

  float xv[4];
  float mn = __builtin_inff(), mx = -__builtin_inff();
#pragma unroll
  for (int e = 0; e < 4; ++e) {
    xv[e] = base[(tid + e * 1024) * 3];
    mn = fminf(mn, xv[e]);
    mx = fmaxf(mx, xv[e]);
  }
#pragma unroll
  for (int o = 32; o > 0; o >>= 1) {
    mn = fminf(mn, __shfl_xor(mn, o));
    mx = fmaxf(mx, __shfl_xor(mx, o));
  }
  if (lane == 0) { wmn[wid] = mn; wmx[wid] = mx; }
  if (tid < NBINS) bins[tid] = 0;
  __syncthreads();                          // B1
  if (tid == 0) {
    float a = wmn[0], c = wmx[0];
#pragma unroll
    for (int w = 1; w < NSEG; ++w) { a = fminf(a, wmn[w]); c = fmaxf(c, wmx[w]); }
    sxmin = a;
    sxscl = (c > a) ? ((float)NBINS / (c - a)) : 0.0f;
    meta[2 * b + 0] = a;
    meta[2 * b + 1] = sxscl;
  }
  __syncthreads();                          // B2
  const float xmn = sxmin, xsc = sxscl;
  int bi[4];
#pragma unroll
  for (int e = 0; e < 4; ++e) {
    int v = (int)((xv[e] - xmn) * xsc);
    v = v < 0 ? 0 : (v > NBINS - 1 ? NBINS - 1 : v);
    bi[e] = v;
    atomicAdd(&bins[v], 1u);
  }
  __syncthreads();                          // B3
  if (tid < 64) {                           // wave 0: exclusive scan of 256 bins
    const unsigned c0 = bins[4 * tid + 0], c1 = bins[4 * tid + 1];
    const unsigned c2 = bins[4 * tid + 2], c3 = bins[4 * tid + 3];
    const unsigned s4 = c0 + c1 + c2 + c3;
    unsigned acc = s4;
#pragma unroll
    for (int o = 1; o < 64; o <<= 1) {
      const unsigned nb = __shfl_up(acc, o);
      if (tid >= o) acc += nb;
    }
    const unsigned ex = acc - s4;
    boff[4 * tid + 0] = ex;
    boff[4 * tid + 1] = ex + c0;
    boff[4 * tid + 2] = ex + c0 + c1;
    boff[4 * tid + 3] = ex + c0 + c1 + c2;
    if (tid == 0) boff[NBINS] = NPTS;
  }
  __syncthreads();                          // B4
  if (tid < NBINS) {
    binoff[b * (NBINS + 1) + tid] = boff[tid];
    bins[tid] = 0;                          // reuse as cursors
  }
  if (tid == 0) binoff[b * (NBINS + 1) + NBINS] = NPTS;
  __syncthreads();                          // B5
#pragma unroll
  for (int e = 0; e < 4; ++e) {
    const int idx = tid + e * 1024;
    const float x = xv[e];
    const float y = base[idx * 3 + 1];
    const float z = base[idx * 3 + 2];
    const unsigned pos = boff[bi[e]] + atomicAdd(&bins[bi[e]], 1u);
    float* dst = spk + (size_t)b * (NPTS * 4) + (size_t)(pos >> 2) * 16 + (pos & 3);
    dst[0]  = x;
    dst[4]  = y;
    dst[8]  = z;
    dst[12] = fmaf(z, z, fmaf(y, y, x * x));  // same form as r_i epilogue
    sorg[b * NPTS + pos] = (unsigned)idx;
  }
}

// Kernel 1: bucketed exact 5-NN. grid = 256 (8 x 32 tiles of 128 scattered
// ranks, 2/lane, all 16 waves share them); 1 block/CU (104 KB LDS).
__global__ __launch_bounds__(TPB, 4) void knn_bucket(const float* __restrict__ spk,
                                                     const unsigned* __restrict__ sorg,
                                                     const unsigned* __restrict__ binoff,
                                                     const float* __restrict__ meta,
                                                     float* __restrict__ value) {
  __shared__ float pk[NPTS * 4];              // 64 KB packed groups (scattered order)
  __shared__ float acand[NSEG][PPB][KSEL];    // 40 KB merge buffer (used twice)
  __shared__ float sblo, sbhi;

  const int tid = threadIdx.x;
  const int pt  = tid & 63;
  const int seg = __builtin_amdgcn_readfirstlane(tid >> 6);  // wave-uniform
  const int b    = blockIdx.x >> 5;   // 32 tiles per batch
  const int tile = blockIdx.x & 31;
  const int T    = tile * PPB;
  const int i0   = T + pt;            // lane's two scattered ranks
  const int i1   = i0 + 64;

  // Stage the batch's packed array (coalesced float4).
  {
    const float4* __restrict__ src = (const float4*)(spk + (size_t)b * (NPTS * 4));
    float4* dst = (float4*)pk;
#pragma unroll
    for (int e = 0; e < (NPTS * 4) / (TPB * 4); ++e)
      dst[tid + e * TPB] = src[tid + e * TPB];
  }
  __syncthreads();

  // Own coords.
  const int gi0 = (i0 >> 2) * 16 + (i0 & 3);
  const int gi1 = (i1 >> 2) * 16 + (i1 & 3);
  const float xi0 = pk[gi0 + 0], yi0 = pk[gi0 + 4], zi0 = pk[gi0 + 8];
  const float xi1 = pk[gi1 + 0], yi1 = pk[gi1 + 4], zi1 = pk[gi1 + 8];
  const float x20 = -2.0f * xi0, y20 = -2.0f * yi0, z20 = -2.0f * zi0;  // exact
  const float x21 = -2.0f * xi1, y21 = -2.0f * yi1, z21 = -2.0f * zi1;
  const float ri0 = fmaf(zi0, zi0, fmaf(yi0, yi0, xi0 * xi0));
  const float ri1 = fmaf(zi1, zi1, fmaf(yi1, yi1, xi1 * xi1));

  const f16v* __restrict__ sg = (const f16v*)pk;

  // ---- Phase a: 256-rank window around the tile, EXACT merged top-5 ----
  float m0[KSEL], m1[KSEL];
#pragma unroll
  for (int k = 0; k < KSEL; ++k) { m0[k] = __builtin_inff(); m1[k] = __builtin_inff(); }

  int a0 = T - 64;
  if (a0 < 0) a0 = 0;
  if (a0 > NPTS - AWIN) a0 = NPTS - AWIN;   // window contains [T, T+PPB)
  const int a0g = a0 >> 2;
#pragma unroll
  for (int q = 0; q < (AWIN / 4) / NSEG; ++q) {   // 4 groups per wave
    const int gg = a0g + seg * ((AWIN / 4) / NSEG) + q;
    const int jb = gg * 4;
    const f16v c = sg[gg];
    if ((unsigned)(jb - T) < (unsigned)PPB)
      knn_group4_sc<true>(c, jb, i0, i1, x20, y20, z20, x21, y21, z21, m0, m1);
    else
      knn_group4_sc<false>(c, jb, i0, i1, x20, y20, z20, x21, y21, z21, m0, m1);
  }
#pragma unroll
  for (int k = 0; k < KSEL; ++k) {
    acand[seg][pt][k]      = m0[k];
    acand[seg][pt + 64][k] = m1[k];
  }
  __syncthreads();
  for (int st = 1; st < NSEG; st <<= 1) {
    const int pairs = NSEG / (2 * st);
    if (tid < pairs * PPB) {
      const int q = tid >> 7;
      const int p = tid & (PPB - 1);
      float* A = &acand[2 * st * q][p][0];
      const float* B = &acand[2 * st * q + st][p][0];
      float mm[KSEL];
#pragma unroll
      for (int k = 0; k < KSEL; ++k) mm[k] = A[k];
#pragma unroll
      for (int k = 0; k < KSEL; ++k) {
        float t = B[k];
#pragma unroll
        for (int u = 0; u < KSEL - 1; ++u) {
          const float lo2 = fminf(mm[u], t);
          t = fmaxf(mm[u], t);
          mm[u] = lo2;
        }
        mm[KSEL - 1] = fminf(mm[KSEL - 1], t);
      }
#pragma unroll
      for (int k = 0; k < KSEL; ++k) A[k] = mm[k];
    }
    __syncthreads();
  }

  // Tight per-point bound; inflate past fp slop (excluded => strictly worse).
  const float d50 = acand[0][pt][KSEL - 1] + ri0;
  const float d51 = acand[0][pt + 64][KSEL - 1] + ri1;
  const float si0 = sqrtf(fmaxf(d50, 0.0f)) * 1.001f + 1e-4f;
  const float si1 = sqrtf(fmaxf(d51, 0.0f)) * 1.001f + 1e-4f;
  if (tid < 64) {   // all waves hold identical values; wave 0 reduces
    float vlo = fminf(xi0 - si0, xi1 - si1);
    float vhi = fmaxf(xi0 + si0, xi1 + si1);
#pragma unroll
    for (int o = 32; o > 0; o >>= 1) {
      vlo = fminf(vlo, __shfl_xor(vlo, o));
      vhi = fmaxf(vhi, __shfl_xor(vhi, o));
    }
    if (tid == 0) { sblo = vlo; sbhi = vhi; }
  }
  __syncthreads();   // also: all acand reads above are done

  // Window via bin boundaries (monotone fp mul + clamp -> exact superset).
  const float xmn = meta[2 * b + 0], xsc = meta[2 * b + 1];
  int binlo = (int)((sblo - xmn) * xsc);
  int binhi = (int)((sbhi - xmn) * xsc);
  binlo = binlo < 0 ? 0 : (binlo > NBINS - 1 ? NBINS - 1 : binlo);
  binhi = binhi < 0 ? 0 : (binhi > NBINS - 1 ? NBINS - 1 : binhi);
  const int cs = (int)binoff[b * (NBINS + 1) + binlo];
  const int ce = (int)binoff[b * (NBINS + 1) + binhi + 1];
  const int glo = cs >> 2;
  const int ghi = (ce + 3) >> 2;

  // ---- Phase b: scan the window, fresh lists, round-robin waves ----
#pragma unroll
  for (int k = 0; k < KSEL; ++k) { m0[k] = __builtin_inff(); m1[k] = __builtin_inff(); }
  int gg = glo + seg;
  for (; gg + NSEG < ghi; gg += 2 * NSEG) {   // 2 groups in flight
    const f16v cA = sg[gg];
    const f16v cB = sg[gg + NSEG];
    const int jbA = gg * 4, jbB = (gg + NSEG) * 4;
    if ((unsigned)(jbA - T) < (unsigned)PPB)
      knn_group4_sc<true>(cA, jbA, i0, i1, x20, y20, z20, x21, y21, z21, m0, m1);
    else
      knn_group4_sc<false>(cA, jbA, i0, i1, x20, y20, z20, x21, y21, z21, m0, m1);
    if ((unsigned)(jbB - T) < (unsigned)PPB)
      knn_group4_sc<true>(cB, jbB, i0, i1, x20, y20, z20, x21, y21, z21, m0, m1);
    else
      knn_group4_sc<false>(cB, jbB, i0, i1, x20, y20, z20, x21, y21, z21, m0, m1);
  }
  if (gg < ghi) {
    const f16v c = sg[gg];
    const int jb = gg * 4;
    if ((unsigned)(jb - T) < (unsigned)PPB)
      knn_group4_sc<true>(c, jb, i0, i1, x20, y20, z20, x21, y21, z21, m0, m1);
    else
      knn_group4_sc<false>(c, jb, i0, i1, x20, y20, z20, x21, y21, z21, m0, m1);
  }

#pragma unroll
  for (int k = 0; k < KSEL; ++k) {
    acand[seg][pt][k]      = m0[k];
    acand[seg][pt + 64][k] = m1[k];
  }
  __syncthreads();
  for (int st = 1; st < NSEG; st <<= 1) {
    const int pairs = NSEG / (2 * st);
    if (tid < pairs * PPB) {
      const int q = tid >> 7;
      const int p = tid & (PPB - 1);
      float* A = &acand[2 * st * q][p][0];
      const float* B = &acand[2 * st * q + st][p][0];
      float mm[KSEL];
#pragma unroll
      for (int k = 0; k < KSEL; ++k) mm[k] = A[k];
#pragma unroll
      for (int k = 0; k < KSEL; ++k) {
        float t = B[k];
#pragma unroll
        for (int u = 0; u < KSEL - 1; ++u) {
          const float lo2 = fminf(mm[u], t);
          t = fmaxf(mm[u], t);
          mm[u] = lo2;
        }
        mm[KSEL - 1] = fminf(mm[KSEL - 1], t);
      }
#pragma unroll
      for (int k = 0; k < KSEL; ++k) A[k] = mm[k];
    }
    __syncthreads();
  }

  // mean(d) = mean(g) + r_i, ascending sum; scatter to ORIGINAL index.
  if (tid < PPB) {
    float s5 = 0.f;
#pragma unroll
    for (int k = 0; k < KSEL; ++k) s5 += acand[0][tid][k];
    const float rr = (tid < 64) ? ri0 : ri1;   // wave0 lane t -> pt T+t; wave1 lane t-64 -> pt T+t
    value[b * NPTS + sorg[b * NPTS + T + tid]] = s5 * 0.2f + rr;
  }
}

// Kernel 2: per-batch stats on value[] (original order). 1024 threads.
__global__ __launch_bounds__(STATS_T) void stats_v(const float* __restrict__ value,
                                                   const float* __restrict__ weights,
                                                   float* __restrict__ out) {
  __shared__ float vbuf[NPTS];
  __shared__ float red[STATS_T];
  const int b   = blockIdx.x;
  const int tid = threadIdx.x;

  float s = 0.f;
  for (int j = tid; j < NPTS; j += STATS_T) {
    const float v = value[b * NPTS + j];
    vbuf[j] = v;
    s += v;
  }
  red[tid] = s;
  __syncthreads();
  for (int off = STATS_T / 2; off > 0; off >>= 1) {
    if (tid < off) red[tid] += red[tid + off];
    __syncthreads();
  }
  const float mean = red[0] * (1.0f / NPTS);
  __syncthreads();

  float s2 = 0.f;
  for (int j = tid; j < NPTS; j += STATS_T) {
    const float d = vbuf[j] - mean;
    s2 += d * d;
  }
  red[tid] = s2;
  __syncthreads();
  for (int off = STATS_T / 2; off > 0; off >>= 1) {
    if (tid < off) red[tid] += red[tid + off];
    __syncthreads();
  }
  const float thr = mean + ALPHA * sqrtf(red[0] * (1.0f / (NPTS - 1)));
  __syncthreads();

  float s3 = 0.f;
  for (int j = tid; j < NPTS; j += STATS_T) {
    const float vv = vbuf[j];
    if (vv > thr) s3 += vv;
  }
  red[tid] = s3;
  __syncthreads();
  for (int off = STATS_T / 2; off > 0; off >>= 1) {
    if (tid < off) red[tid] += red[tid + off];
    __syncthreads();
  }
  if (tid == 0) {
    atomicAdd(out, red[0] * (1.0f / NPTS) * weights[b] * (1.0f / BATCH));
  }
}

// ---------------------------------------------------------------------------
// Fallback (ws too small): R10 brute-force kernel, unchanged.
// ---------------------------------------------------------------------------
template <bool EXCL>
static __device__ __forceinline__ void scan_seg_sc2(const f16v* __restrict__ sg,
                                                    const int g0i, const int j0,
                                                    const int i0, const int i1,
                                                    const float x20, const float y20, const float z20,
                                                    const float x21, const float y21, const float z21,
                                                    float m0[KSEL], float m1[KSEL]) {
#pragma unroll 4
  for (int g = 0; g < SEGLEN / 4; ++g) {
    const f16v c = sg[g0i + g];
    knn_group4_sc<EXCL>(c, j0 + 4 * g, i0, i1, x20, y20, z20, x21, y21, z21, m0, m1);
  }
}

__global__ __launch_bounds__(TPB) void knn_value_sc2(const float* __restrict__ pc,
                                                     float* __restrict__ value,
                                                     float* __restrict__ out) {
  __shared__ union __align__(64) {
    float pk[NPTS * 4];
    float cand[NSEG][PPB][KSEL];
  } sh;

  const int tid = threadIdx.x;
  const int pt  = tid & 63;
  const int seg = __builtin_amdgcn_readfirstlane(tid >> 6);
  const int b    = blockIdx.x >> 5;
  const int tile = blockIdx.x & 31;
  const int i0   = tile * PPB + pt;
  const int i1   = i0 + 64;

  if (blockIdx.x == 0 && tid == 0) out[0] = 0.0f;

  const float* __restrict__ base = pc + (size_t)b * (NPTS * 3);
#pragma unroll
  for (int k = 0; k < NPTS / TPB; ++k) {
    const int p = tid + k * TPB;
    const float x = base[p * 3 + 0];
    const float y = base[p * 3 + 1];
    const float z = base[p * 3 + 2];
    float* dst = &sh.pk[(p >> 2) * 16];
    const int s = p & 3;
    dst[s + 0]  = x;
    dst[s + 4]  = y;
    dst[s + 8]  = z;
    dst[s + 12] = fmaf(z, z, fmaf(y, y, x * x));
  }
  __syncthreads();

  const int gi0 = (i0 >> 2) * 16 + (i0 & 3);
  const int gi1 = (i1 >> 2) * 16 + (i1 & 3);
  const float xi0 = sh.pk[gi0 + 0], yi0 = sh.pk[gi0 + 4], zi0 = sh.pk[gi0 + 8];
  const float xi1 = sh.pk[gi1 + 0], yi1 = sh.pk[gi1 + 4], zi1 = sh.pk[gi1 + 8];
  const float x20 = -2.0f * xi0, y20 = -2.0f * yi0, z20 = -2.0f * zi0;
  const float x21 = -2.0f * xi1, y21 = -2.0f * yi1, z21 = -2.0f * zi1;

  float m0[KSEL], m1[KSEL];
#pragma unroll
  for (int k = 0; k < KSEL; ++k) { m0[k] = __builtin_inff(); m1[k] = __builtin_inff(); }

  const int j0  = seg * SEGLEN;
  const int g0i = seg * (SEGLEN / 4);
  const f16v* __restrict__ sg = (const f16v*)sh.pk;

  if (seg == (tile >> 1)) {
    scan_seg_sc2<true>(sg, g0i, j0, i0, i1, x20, y20, z20, x21, y21, z21, m0, m1);
  } else {
    scan_seg_sc2<false>(sg, g0i, j0, i0, i1, x20, y20, z20, x21, y21, z21, m0, m1);
  }
  __syncthreads();

#pragma unroll
  for (int k = 0; k < KSEL; ++k) {
    sh.cand[seg][pt][k]      = m0[k];
    sh.cand[seg][pt + 64][k] = m1[k];
  }
  __syncthreads();

  for (int st = 1; st < NSEG; st <<= 1) {
    const int pairs = NSEG / (2 * st);
    if (tid < pairs * PPB) {
      const int q = tid >> 7;
      const int p = tid & (PPB - 1);
      float* A = &sh.cand[2 * st * q][p][0];
      const float* B = &sh.cand[2 * st * q + st][p][0];
      float mm[KSEL];
#pragma unroll
      for (int k = 0; k < KSEL; ++k) mm[k] = A[k];
#pragma unroll
      for (int k = 0; k < KSEL; ++k) {
        float t = B[k];
#pragma unroll
        for (int u = 0; u < KSEL - 1; ++u) {
          const float lo = fminf(mm[u], t);
          t = fmaxf(mm[u], t);
          mm[u] = lo;
        }
        mm[KSEL - 1] = fminf(mm[KSEL - 1], t);
      }
#pragma unroll
      for (int k = 0; k < KSEL; ++k) A[k] = mm[k];
    }
    __syncthreads();
  }

  if (tid < PPB) {
    float s5 = 0.f;
#pragma unroll
    for (int k = 0; k < KSEL; ++k) s5 += sh.cand[0][tid][k];
    float xx, yy, zz;
    if (tid < 64) { xx = xi0; yy = yi0; zz = zi0; }
    else          { xx = xi1; yy = yi1; zz = zi1; }
    const float ri = fmaf(zz, zz, fmaf(yy, yy, xx * xx));
    value[b * NPTS + tile * PPB + tid] = s5 * 0.2f + ri;
  }
}

extern "C" void kernel_launch(void* const* d_in, const int* in_sizes, int n_in,
                              void* d_out, int out_size, void* d_ws, size_t ws_size,
                              hipStream_t stream) {
  const float* pc      = (const float*)d_in[0];   // [8,4096,3] f32
  const float* weights = (const float*)d_in[1];   // [8] f32
  float* out   = (float*)d_out;                   // scalar f32
  float* wsf   = (float*)d_ws;

  const size_t NB = (size_t)BATCH * NPTS;          // 32768
  // layout: value NB | spk 4NB | sorg NB | binoff 8*(NBINS+1) | meta 16
  const size_t need = (NB * 6 + (size_t)BATCH * (NBINS + 1) + 16) * 4;

  if (ws_size >= need) {
    float*    value  = wsf;
    float*    spk    = wsf + NB;
    unsigned* sorg   = (unsigned*)(wsf + 5 * NB);
    unsigned* binoff = (unsigned*)(wsf + 6 * NB);
    float*    meta   = (float*)(wsf + 6 * NB) + BATCH * (NBINS + 1);
    bucket_kernel<<<dim3(BATCH), dim3(1024), 0, stream>>>(pc, spk, sorg, binoff, meta, out);
    knn_bucket<<<dim3(BATCH * 32), dim3(TPB), 0, stream>>>(spk, sorg, binoff, meta, value);
    stats_v<<<dim3(BATCH), dim3(STATS_T), 0, stream>>>(value, weights, out);
  } else {
    float* value = wsf;                           // 128 KB (R10 layout)
    knn_value_sc2<<<dim3(BATCH * (NPTS / PPB)), dim3(TPB), 0, stream>>>(pc, value, out);
    stats_v<<<dim3(BATCH), dim3(STATS_T), 0, stream>>>(value, weights, out);
  }
}

// Round 15
// 94.883 us; speedup vs baseline: 1.5999x; 1.1851x over previous
//
#include <hip/hip_runtime.h>

#define BATCH 8
#define NPTS 4096
#define KSEL 5          // K_NN; self-candidate excluded in-scan
#define ALPHA 1.05f
#define NSEG 16         // waves per block
#define TPB (NSEG * 64)        // 1024 threads
#define PPB 128         // points per block (2 per lane)
#define HALF 2048              // candidates per half-block (fast path)
#define HSEGLEN (HALF / NSEG)  // 128 candidates per wave
#define SEGLEN (NPTS / NSEG)   // 256 (fallback kernel)
#define STATS_T 1024

// ---------------------------------------------------------------------------
// f32 3-input min/med/max (single VOP3 instr each). Selection runs in FLOAT
// domain (g-scores can be negative). No NaNs present.
// ---------------------------------------------------------------------------
static __device__ __forceinline__ float min3f(float a, float b, float c) {
  float d;
  asm("v_min3_f32 %0, %1, %2, %3" : "=v"(d) : "v"(a), "v"(b), "v"(c));
  return d;
}
static __device__ __forceinline__ float med3f(float a, float b, float c) {
  float d;
  asm("v_med3_f32 %0, %1, %2, %3" : "=v"(d) : "v"(a), "v"(b), "v"(c));
  return d;
}
static __device__ __forceinline__ float max3f(float a, float b, float c) {
  float d;
  asm("v_max3_f32 %0, %1, %2, %3" : "=v"(d) : "v"(a), "v"(b), "v"(c));
  return d;
}

typedef float f16v __attribute__((ext_vector_type(16)));  // one 64B packed group

// Fused branchless insert of two candidates into sorted m[0..KSEL-1], float.
// 13 ops / 2 candidates — count-optimal for exact streaming top-5.
static __device__ __forceinline__ void insert2f(float m[KSEL], float tA, float tB) {
#pragma unroll
  for (int k = 0; k < KSEL - 1; ++k) {
    const float mk = m[k];
    m[k] = min3f(mk, tA, tB);
    const float nA = med3f(mk, tA, tB);
    const float nB = max3f(mk, tA, tB);
    tA = nA;
    tB = nB;
  }
  m[KSEL - 1] = min3f(m[KSEL - 1], tA, tB);
}

// ---------------------------------------------------------------------------
// R14 post-mortem: bucket-pruning did 79% of brute-force VALU work (block
// UNION window ~2500/4096 cands: tail s_i + equal-count tile x-span + bin
// rounding) at 1 block/CU (4 waves/SIMD, issue ~0.6) -> 52.5us > brute 41.
// R15 = RESTORE R12, the measured optimum (94.46us total): 2-half split,
// 2 blocks/CU = 8 waves/SIMD (issue 0.82), all-scalar 3-fma expansion-form
// distance g = fma(x_j,-2x_i, fma(y_j,-2y_i, fma(z_j,-2z_i, r_j))),
// min3/med3/max3 insert network, fused half-merge stats at 1024 threads.
// Remaining headroom vs the 82k-instr issue floor is ~5us; fixed harness
// overhead (~51us) dominates the total.
// ---------------------------------------------------------------------------
template <bool EXCL>
static __device__ __forceinline__ void knn_group4_sc(const f16v c, const int jb,
                                                     const int i0, const int i1,
                                                     const float x20, const float y20, const float z20,
                                                     const float x21, const float y21, const float z21,
                                                     float m0[KSEL], float m1[KSEL]) {
  // layout: c[0..3]=x, c[4..7]=y, c[8..11]=z, c[12..15]=r
  float g0[4], g1[4];
#pragma unroll
  for (int t = 0; t < 4; ++t) {
    const float xj = c[t], yj = c[4 + t], zj = c[8 + t], rj = c[12 + t];
    g0[t] = fmaf(xj, x20, fmaf(yj, y20, fmaf(zj, z20, rj)));
    g1[t] = fmaf(xj, x21, fmaf(yj, y21, fmaf(zj, z21, rj)));
  }
  if (EXCL) {
#pragma unroll
    for (int t = 0; t < 4; ++t) {
      if (jb + t == i0) g0[t] = __builtin_inff();
      if (jb + t == i1) g1[t] = __builtin_inff();
    }
  }
  insert2f(m0, g0[0], g0[1]);
  insert2f(m0, g0[2], g0[3]);
  insert2f(m1, g1[0], g1[1]);
  insert2f(m1, g1[2], g1[3]);
}

template <bool EXCL>
static __device__ __forceinline__ void scan_half(const f16v* __restrict__ sg,
                                                 const int gbase, const int jb0,
                                                 const int i0, const int i1,
                                                 const float x20, const float y20, const float z20,
                                                 const float x21, const float y21, const float z21,
                                                 float m0[KSEL], float m1[KSEL]) {
#pragma unroll 8
  for (int g = 0; g < HSEGLEN / 4; ++g) {   // 32 groups of 4 candidates
    const f16v c = sg[gbase + g];
    knn_group4_sc<EXCL>(c, jb0 + 4 * g, i0, i1, x20, y20, z20, x21, y21, z21, m0, m1);
  }
}

// ---------------------------------------------------------------------------
// Kernel 1 (fast path): partial top-5 over one candidate half.
// grid = 512 blocks = 8 batches x 32 tiles x 2 halves; 1024 threads (16
// waves); 2 blocks/CU -> 8 waves/SIMD. Each wave scans 128 candidates for
// the tile's 128 points (2/lane). Output: part[k][b][half][point] (SoA).
// ---------------------------------------------------------------------------
__global__ __launch_bounds__(TPB, 8) void knn_half(const float* __restrict__ pc,
                                                   float* __restrict__ part,
                                                   float* __restrict__ out) {
  __shared__ union __align__(64) {
    float pk[HALF * 4];              // 512 groups x {x[4],y[4],z[4],r[4]} = 32 KB
    float cand[NSEG][PPB][KSEL];     // 40 KB (reused after scan)
  } sh;

  const int tid = threadIdx.x;
  const int pt  = tid & 63;
  const int seg = __builtin_amdgcn_readfirstlane(tid >> 6);  // wave-uniform
  const int b    = blockIdx.x >> 6;          // 64 blocks per batch
  const int rr   = blockIdx.x & 63;
  const int tile = rr >> 1;                  // 32 tiles of 128 points
  const int half = rr & 1;                   // candidate half

  if (blockIdx.x == 0 && tid == 0) out[0] = 0.0f;  // stats kernel accumulates

  const float* __restrict__ base = pc + (size_t)b * (NPTS * 3);

  // ---- Stage this half's 2048 points: 2 per thread, packed groups + r ----
#pragma unroll
  for (int k = 0; k < HALF / TPB; ++k) {
    const int pl = tid + k * TPB;            // local point 0..2047
    const int gp = half * HALF + pl;         // global point in batch
    const float x = base[gp * 3 + 0];
    const float y = base[gp * 3 + 1];
    const float z = base[gp * 3 + 2];
    float* dst = &sh.pk[(pl >> 2) * 16];
    const int s = pl & 3;
    dst[s + 0]  = x;
    dst[s + 4]  = y;
    dst[s + 8]  = z;
    dst[s + 12] = fmaf(z, z, fmaf(y, y, x * x));  // same form as stats r_i
  }

  // Own two points (may live in the OTHER half -> read straight from pc).
  const int i0 = tile * PPB + pt;
  const int i1 = i0 + 64;
  const float xi0 = base[i0 * 3 + 0], yi0 = base[i0 * 3 + 1], zi0 = base[i0 * 3 + 2];
  const float xi1 = base[i1 * 3 + 0], yi1 = base[i1 * 3 + 1], zi1 = base[i1 * 3 + 2];
  // -2*x_i is EXACT (exponent bump + sign).
  const float x20 = -2.0f * xi0, y20 = -2.0f * yi0, z20 = -2.0f * zi0;
  const float x21 = -2.0f * xi1, y21 = -2.0f * yi1, z21 = -2.0f * zi1;

  __syncthreads();

  float m0[KSEL], m1[KSEL];
#pragma unroll
  for (int k = 0; k < KSEL; ++k) { m0[k] = __builtin_inff(); m1[k] = __builtin_inff(); }

  const int jb0   = half * HALF + seg * HSEGLEN;  // global candidate base
  const int gbase = seg * (HSEGLEN / 4);
  const f16v* __restrict__ sg = (const f16v*)sh.pk;

  // The tile's 128 point indices occupy exactly one 128-candidate wave
  // segment: (half*16 + seg) == tile. Only that wave pays the compares.
  if (half * NSEG + seg == tile) {
    scan_half<true>(sg, gbase, jb0, i0, i1, x20, y20, z20, x21, y21, z21, m0, m1);
  } else {
    scan_half<false>(sg, gbase, jb0, i0, i1, x20, y20, z20, x21, y21, z21, m0, m1);
  }
  __syncthreads();  // all waves done reading the stage buffer

#pragma unroll
  for (int k = 0; k < KSEL; ++k) {
    sh.cand[seg][pt][k]      = m0[k];
    sh.cand[seg][pt + 64][k] = m1[k];
  }
  __syncthreads();

  // Tree-merge the 16 sorted lists per point: 8,4,2,1 pairwise merges.
  for (int st = 1; st < NSEG; st <<= 1) {
    const int pairs = NSEG / (2 * st);
    if (tid < pairs * PPB) {
      const int q = tid >> 7;
      const int p = tid & (PPB - 1);
      float* A = &sh.cand[2 * st * q][p][0];
      const float* B = &sh.cand[2 * st * q + st][p][0];
      float mm[KSEL];
#pragma unroll
      for (int k = 0; k < KSEL; ++k) mm[k] = A[k];
#pragma unroll
      for (int k = 0; k < KSEL; ++k) {
        float t = B[k];
#pragma unroll
        for (int u = 0; u < KSEL - 1; ++u) {
          const float lo = fminf(mm[u], t);
          t = fmaxf(mm[u], t);
          mm[u] = lo;
        }
        mm[KSEL - 1] = fminf(mm[KSEL - 1], t);
      }
#pragma unroll
      for (int k = 0; k < KSEL; ++k) A[k] = mm[k];
    }
    __syncthreads();
  }

  // Write this half's sorted partial top-5 (SoA by k for coalescing).
  if (tid < PPB) {
    const int p = tile * PPB + tid;
#pragma unroll
    for (int k = 0; k < KSEL; ++k) {
      part[(((size_t)k * BATCH + b) * 2 + half) * NPTS + p] = sh.cand[0][tid][k];
    }
  }
}

// ---------------------------------------------------------------------------
// Kernel 2 (fast path): fused half-merge + per-batch stats. 1024 threads
// (4 waves/SIMD). Pass 1 merges the two sorted-5 partials per point (exact
// top-5 of all 4096 candidates), adds r_i, caches value in LDS, accumulates
// mean. Passes 2-3 reuse the LDS copy.
// ---------------------------------------------------------------------------
__global__ __launch_bounds__(STATS_T) void stats_fused(const float* __restrict__ part,
                                                       const float* __restrict__ pc,
                                                       const float* __restrict__ weights,
                                                       float* __restrict__ out) {
  __shared__ float vbuf[NPTS];   // 16 KB merged values
  __shared__ float red[STATS_T];
  const int b   = blockIdx.x;
  const int tid = threadIdx.x;

  // pass 1: merge + value + mean
  float s = 0.f;
  for (int j = tid; j < NPTS; j += STATS_T) {
    float mm[KSEL];
#pragma unroll
    for (int k = 0; k < KSEL; ++k)
      mm[k] = part[(((size_t)k * BATCH + b) * 2 + 0) * NPTS + j];
#pragma unroll
    for (int k = 0; k < KSEL; ++k) {
      float t = part[(((size_t)k * BATCH + b) * 2 + 1) * NPTS + j];
#pragma unroll
      for (int u = 0; u < KSEL - 1; ++u) {
        const float lo = fminf(mm[u], t);
        t = fmaxf(mm[u], t);
        mm[u] = lo;
      }
      mm[KSEL - 1] = fminf(mm[KSEL - 1], t);
    }
    float s5 = 0.f;
#pragma unroll
    for (int k = 0; k < KSEL; ++k) s5 += mm[k];  // ascending sum, as before
    const float x = pc[((size_t)b * NPTS + j) * 3 + 0];
    const float y = pc[((size_t)b * NPTS + j) * 3 + 1];
    const float z = pc[((size_t)b * NPTS + j) * 3 + 2];
    const float v = s5 * 0.2f + fmaf(z, z, fmaf(y, y, x * x));
    vbuf[j] = v;
    s += v;
  }
  red[tid] = s;
  __syncthreads();
  for (int off = STATS_T / 2; off > 0; off >>= 1) {
    if (tid < off) red[tid] += red[tid + off];
    __syncthreads();
  }
  const float mean = red[0] * (1.0f / NPTS);
  __syncthreads();

  // pass 2: unbiased std
  float s2 = 0.f;
  for (int j = tid; j < NPTS; j += STATS_T) {
    const float d = vbuf[j] - mean;
    s2 += d * d;
  }
  red[tid] = s2;
  __syncthreads();
  for (int off = STATS_T / 2; off > 0; off >>= 1) {
    if (tid < off) red[tid] += red[tid + off];
    __syncthreads();
  }
  const float thr = mean + ALPHA * sqrtf(red[0] * (1.0f / (NPTS - 1)));
  __syncthreads();

  // pass 3: masked sum (strict >)
  float s3 = 0.f;
  for (int j = tid; j < NPTS; j += STATS_T) {
    const float vv = vbuf[j];
    if (vv > thr) s3 += vv;
  }
  red[tid] = s3;
  __syncthreads();
  for (int off = STATS_T / 2; off > 0; off >>= 1) {
    if (tid < off) red[tid] += red[tid + off];
    __syncthreads();
  }
  if (tid == 0) {
    atomicAdd(out, red[0] * (1.0f / NPTS) * weights[b] * (1.0f / BATCH));
  }
}

// ---------------------------------------------------------------------------
// Fallback (ws too small for part buffer): R10 brute-force kernels.
// ---------------------------------------------------------------------------
template <bool EXCL>
static __device__ __forceinline__ void scan_seg_sc2(const f16v* __restrict__ sg,
                                                    const int g0i, const int j0,
                                                    const int i0, const int i1,
                                                    const float x20, const float y20, const float z20,
                                                    const float x21, const float y21, const float z21,
                                                    float m0[KSEL], float m1[KSEL]) {
#pragma unroll 4
  for (int g = 0; g < SEGLEN / 4; ++g) {
    const f16v c = sg[g0i + g];
    knn_group4_sc<EXCL>(c, j0 + 4 * g, i0, i1, x20, y20, z20, x21, y21, z21, m0, m1);
  }
}

__global__ __launch_bounds__(TPB) void knn_value_sc2(const float* __restrict__ pc,
                                                     float* __restrict__ value,
                                                     float* __restrict__ out) {
  __shared__ union __align__(64) {
    float pk[NPTS * 4];
    float cand[NSEG][PPB][KSEL];
  } sh;

  const int tid = threadIdx.x;
  const int pt  = tid & 63;
  const int seg = __builtin_amdgcn_readfirstlane(tid >> 6);
  const int b    = blockIdx.x >> 5;
  const int tile = blockIdx.x & 31;
  const int i0   = tile * PPB + pt;
  const int i1   = i0 + 64;

  if (blockIdx.x == 0 && tid == 0) out[0] = 0.0f;

  const float* __restrict__ base = pc + (size_t)b * (NPTS * 3);
#pragma unroll
  for (int k = 0; k < NPTS / TPB; ++k) {
    const int p = tid + k * TPB;
    const float x = base[p * 3 + 0];
    const float y = base[p * 3 + 1];
    const float z = base[p * 3 + 2];
    float* dst = &sh.pk[(p >> 2) * 16];
    const int s = p & 3;
    dst[s + 0]  = x;
    dst[s + 4]  = y;
    dst[s + 8]  = z;
    dst[s + 12] = fmaf(z, z, fmaf(y, y, x * x));
  }
  __syncthreads();

  const int gi0 = (i0 >> 2) * 16 + (i0 & 3);
  const int gi1 = (i1 >> 2) * 16 + (i1 & 3);
  const float xi0 = sh.pk[gi0 + 0], yi0 = sh.pk[gi0 + 4], zi0 = sh.pk[gi0 + 8];
  const float xi1 = sh.pk[gi1 + 0], yi1 = sh.pk[gi1 + 4], zi1 = sh.pk[gi1 + 8];
  const float x20 = -2.0f * xi0, y20 = -2.0f * yi0, z20 = -2.0f * zi0;
  const float x21 = -2.0f * xi1, y21 = -2.0f * yi1, z21 = -2.0f * zi1;

  float m0[KSEL], m1[KSEL];
#pragma unroll
  for (int k = 0; k < KSEL; ++k) { m0[k] = __builtin_inff(); m1[k] = __builtin_inff(); }

  const int j0  = seg * SEGLEN;
  const int g0i = seg * (SEGLEN / 4);
  const f16v* __restrict__ sg = (const f16v*)sh.pk;

  if (seg == (tile >> 1)) {
    scan_seg_sc2<true>(sg, g0i, j0, i0, i1, x20, y20, z20, x21, y21, z21, m0, m1);
  } else {
    scan_seg_sc2<false>(sg, g0i, j0, i0, i1, x20, y20, z20, x21, y21, z21, m0, m1);
  }
  __syncthreads();

#pragma unroll
  for (int k = 0; k < KSEL; ++k) {
    sh.cand[seg][pt][k]      = m0[k];
    sh.cand[seg][pt + 64][k] = m1[k];
  }
  __syncthreads();

  for (int st = 1; st < NSEG; st <<= 1) {
    const int pairs = NSEG / (2 * st);
    if (tid < pairs * PPB) {
      const int q = tid >> 7;
      const int p = tid & (PPB - 1);
      float* A = &sh.cand[2 * st * q][p][0];
      const float* B = &sh.cand[2 * st * q + st][p][0];
      float mm[KSEL];
#pragma unroll
      for (int k = 0; k < KSEL; ++k) mm[k] = A[k];
#pragma unroll
      for (int k = 0; k < KSEL; ++k) {
        float t = B[k];
#pragma unroll
        for (int u = 0; u < KSEL - 1; ++u) {
          const float lo = fminf(mm[u], t);
          t = fmaxf(mm[u], t);
          mm[u] = lo;
        }
        mm[KSEL - 1] = fminf(mm[KSEL - 1], t);
      }
#pragma unroll
      for (int k = 0; k < KSEL; ++k) A[k] = mm[k];
    }
    __syncthreads();
  }

  if (tid < PPB) {
    float s5 = 0.f;
#pragma unroll
    for (int k = 0; k < KSEL; ++k) s5 += sh.cand[0][tid][k];
    float xx, yy, zz;
    if (tid < 64) { xx = xi0; yy = yi0; zz = zi0; }
    else          { xx = xi1; yy = yi1; zz = zi1; }
    const float ri = fmaf(zz, zz, fmaf(yy, yy, xx * xx));
    value[b * NPTS + tile * PPB + tid] = s5 * 0.2f + ri;
  }
}

__global__ __launch_bounds__(256) void stats_kernel(const float* __restrict__ value,
                                                    const float* __restrict__ weights,
                                                    float* __restrict__ out) {
  __shared__ float red[256];
  const int b   = blockIdx.x;
  const int tid = threadIdx.x;
  const float* __restrict__ v = value + b * NPTS;

  float s = 0.f;
  for (int j = tid; j < NPTS; j += 256) s += v[j];
  red[tid] = s;
  __syncthreads();
  for (int off = 128; off > 0; off >>= 1) {
    if (tid < off) red[tid] += red[tid + off];
    __syncthreads();
  }
  const float mean = red[0] * (1.0f / NPTS);
  __syncthreads();

  float s2 = 0.f;
  for (int j = tid; j < NPTS; j += 256) {
    const float d = v[j] - mean;
    s2 += d * d;
  }
  red[tid] = s2;
  __syncthreads();
  for (int off = 128; off > 0; off >>= 1) {
    if (tid < off) red[tid] += red[tid + off];
    __syncthreads();
  }
  const float thr = mean + ALPHA * sqrtf(red[0] * (1.0f / (NPTS - 1)));
  __syncthreads();

  float s3 = 0.f;
  for (int j = tid; j < NPTS; j += 256) {
    const float vv = v[j];
    if (vv > thr) s3 += vv;
  }
  red[tid] = s3;
  __syncthreads();
  for (int off = 128; off > 0; off >>= 1) {
    if (tid < off) red[tid] += red[tid + off];
    __syncthreads();
  }
  if (tid == 0) {
    atomicAdd(out, red[0] * (1.0f / NPTS) * weights[b] * (1.0f / BATCH));
  }
}

extern "C" void kernel_launch(void* const* d_in, const int* in_sizes, int n_in,
                              void* d_out, int out_size, void* d_ws, size_t ws_size,
                              hipStream_t stream) {
  const float* pc      = (const float*)d_in[0];   // [8,4096,3] f32
  const float* weights = (const float*)d_in[1];   // [8] f32
  float* out   = (float*)d_out;                   // scalar f32
  float* wsf   = (float*)d_ws;

  const size_t partf = (size_t)KSEL * BATCH * 2 * NPTS;       // 327680 floats
  const size_t need  = partf * sizeof(float);                 // 1.31 MB

  if (ws_size >= need) {
    float* part = wsf;
    knn_half<<<dim3(BATCH * 64), dim3(TPB), 0, stream>>>(pc, part, out);
    stats_fused<<<dim3(BATCH), dim3(STATS_T), 0, stream>>>(part, pc, weights, out);
  } else {
    float* value = wsf;                           // 128 KB (R10 layout)
    knn_value_sc2<<<dim3(BATCH * (NPTS / PPB)), dim3(TPB), 0, stream>>>(pc, value, out);
    stats_kernel<<<dim3(BATCH), dim3(256), 0, stream>>>(value, weights, out);
  }
}